// Round 3
// baseline (359.783 us; speedup 1.0000x reference)
//
#include <hip/hip_runtime.h>
#include <stdint.h>

#define NCH    1024
#define HW     65536    // 256*256 floats per channel
#define TOPK   256
#define PARTS  2        // blocks per channel
#define BLK    256      // threads per partial block
// each block sums HW/PARTS = 32768 floats = 8192 float4; 32 float4/thread

// ---------------------------------------------------------------------------
// Kernel 1: per-channel partial sums. 2 blocks per channel -> 2048 blocks =
// exactly 8 blocks/CU * 4 waves = 32 waves/CU (full occupancy, single pass).
// fp32 pair-sum (x+y),(z+w) then fp64 accumulate: halves fp64 VALU ops;
// added rounding error ~2e-10 on the mean, far below the ~1e-8 min gap
// between adjacent channel means (and below numpy's own pairwise error).
// ---------------------------------------------------------------------------
__global__ __launch_bounds__(BLK, 8) void channel_partial_kernel(
    const float* __restrict__ x, double* __restrict__ partials) {
    const int b    = blockIdx.x;
    const int c    = b >> 1;         // channel
    const int part = b & 1;          // half within channel
    const int tid  = threadIdx.x;

    const float4* p = (const float4*)(x + ((size_t)c << 16) + ((size_t)part << 15));

    double a0 = 0.0, a1 = 0.0, a2 = 0.0, a3 = 0.0;
    #pragma unroll
    for (int t = 0; t < 32; t += 4) {
        float4 v0 = p[tid + (t + 0) * BLK];
        float4 v1 = p[tid + (t + 1) * BLK];
        float4 v2 = p[tid + (t + 2) * BLK];
        float4 v3 = p[tid + (t + 3) * BLK];
        a0 += (double)(v0.x + v0.y) + (double)(v0.z + v0.w);
        a1 += (double)(v1.x + v1.y) + (double)(v1.z + v1.w);
        a2 += (double)(v2.x + v2.y) + (double)(v2.z + v2.w);
        a3 += (double)(v3.x + v3.y) + (double)(v3.z + v3.w);
    }
    double acc = (a0 + a1) + (a2 + a3);

    // wave (64-lane) shuffle reduction
    #pragma unroll
    for (int off = 32; off > 0; off >>= 1)
        acc += __shfl_down(acc, off, 64);

    __shared__ double lds[BLK / 64];
    const int wave = tid >> 6;
    const int lane = tid & 63;
    if (lane == 0) lds[wave] = acc;
    __syncthreads();
    if (tid == 0) {
        double s = ((lds[0] + lds[1]) + lds[2]) + lds[3];
        partials[b] = s;
    }
}

// ---------------------------------------------------------------------------
// Kernel 2: combine partials -> mean, then descending bitonic sort of 1024
// (mean, index) keys. Stages with j<=32 are intra-wave (wave64) -> register
// shuffles; LDS exchange only for j>=64.
// Key = (ordered_uint(float) << 32) | (0xFFFFFFFF - idx): descending sort
// gives descending means, ties broken by lower index (matches lax.top_k).
// ---------------------------------------------------------------------------
__device__ __forceinline__ unsigned long long bitonic_step(
    unsigned long long key, unsigned long long partner, int tid, int k, int j) {
    const bool keep_max = (((tid & k) == 0) == ((tid & j) == 0));
    if (keep_max) return (key > partner) ? key : partner;
    return (key < partner) ? key : partner;
}

__global__ __launch_bounds__(1024) void topk_kernel(
    const double* __restrict__ partials, int* __restrict__ out) {
    __shared__ unsigned long long keys[NCH];
    const int tid = threadIdx.x;

    // deterministic combine of the partials (fixed order)
    const double* p = partials + (size_t)tid * PARTS;
    double s = p[0] + p[1];
    float f = (float)(s * (1.0 / (double)HW));

    unsigned int u = __float_as_uint(f);
    u = (u & 0x80000000u) ? ~u : (u | 0x80000000u);  // order-preserving map
    unsigned long long key = ((unsigned long long)u << 32) |
                             (unsigned long long)(0xFFFFFFFFu - (unsigned)tid);

    // phases k=2..64: entirely intra-wave (j<=32)
    #pragma unroll
    for (int k = 2; k <= 64; k <<= 1) {
        #pragma unroll
        for (int j = k >> 1; j > 0; j >>= 1) {
            unsigned long long partner = __shfl_xor(key, j, 64);
            key = bitonic_step(key, partner, tid, k, j);
        }
    }

    // phases k=128..1024: LDS exchange for j>=64, shuffles for j<=32
    #pragma unroll
    for (int k = 128; k <= 1024; k <<= 1) {
        for (int j = k >> 1; j >= 64; j >>= 1) {
            __syncthreads();               // previous readers done
            keys[tid] = key;
            __syncthreads();
            unsigned long long partner = keys[tid ^ j];
            key = bitonic_step(key, partner, tid, k, j);
        }
        #pragma unroll
        for (int j = 32; j > 0; j >>= 1) {
            unsigned long long partner = __shfl_xor(key, j, 64);
            key = bitonic_step(key, partner, tid, k, j);
        }
    }

    if (tid < TOPK) {
        out[tid] = (int)(0xFFFFFFFFu - (unsigned)(key & 0xFFFFFFFFull));
    }
}

extern "C" void kernel_launch(void* const* d_in, const int* in_sizes, int n_in,
                              void* d_out, int out_size, void* d_ws, size_t ws_size,
                              hipStream_t stream) {
    const float* x     = (const float*)d_in[0];
    double* partials   = (double*)d_ws;   // 2048 doubles of scratch
    int*    out        = (int*)d_out;     // 256 int32 indices

    channel_partial_kernel<<<NCH * PARTS, BLK, 0, stream>>>(x, partials);
    topk_kernel<<<1, NCH, 0, stream>>>(partials, out);
}